// Round 3
// baseline (762.217 us; speedup 1.0000x reference)
//
#include <hip/hip_runtime.h>
#include <math.h>

// Problem constants (B, S, D, MAXOBJ) = (512, 77, 2048, 4)
#define B_ 512
#define S_ 77
#define D_ 2048
#define EPS_ 1e-5f

typedef __attribute__((ext_vector_type(8))) short bf16x8;
typedef __attribute__((ext_vector_type(4))) float f32x4;

// fp32 -> bf16 bits, round-to-nearest-even
__device__ __forceinline__ unsigned short f2bf(float f) {
  union { float f; unsigned u; } x; x.f = f;
  return (unsigned short)((x.u + 0x7FFFu + ((x.u >> 16) & 1u)) >> 16);
}

// block=256 reduction of (sum, sumsq)
__device__ __forceinline__ void blockReduce2(float& a, float& b, float* sbuf) {
  #pragma unroll
  for (int off = 32; off > 0; off >>= 1) {
    a += __shfl_down(a, off, 64);
    b += __shfl_down(b, off, 64);
  }
  int lane = threadIdx.x & 63, wid = threadIdx.x >> 6;
  if (lane == 0) { sbuf[wid * 2] = a; sbuf[wid * 2 + 1] = b; }
  __syncthreads();
  if (threadIdx.x == 0) {
    float sa = 0.f, sb = 0.f;
    #pragma unroll
    for (int w = 0; w < 4; w++) { sa += sbuf[w * 2]; sb += sbuf[w * 2 + 1]; }
    sbuf[8] = sa; sbuf[9] = sb;
  }
  __syncthreads();
  a = sbuf[8]; b = sbuf[9];
}

// ---------------- mega streaming kernel: wcvt (z=0..3), prep (z=4), bulk copy (z=5) ----------------
// All paths are pure-BW streaming with high TLP -> they share HBM bandwidth cleanly.
// The latency-sensitive GEMMs run AFTER this with the memory system unloaded.
__global__ __launch_bounds__(256)
void mega_stream_kernel(const float* __restrict__ w1, const float* __restrict__ w2,
                        const float* __restrict__ w3, const float* __restrict__ w4,
                        unsigned short* __restrict__ o1, unsigned short* __restrict__ o2,
                        unsigned short* __restrict__ o3, unsigned short* __restrict__ o4,
                        const float* __restrict__ x_embed, const float* __restrict__ obj,
                        const int* __restrict__ mask, const int* __restrict__ nobj,
                        const float* __restrict__ g, const float* __restrict__ bb,
                        int* __restrict__ idx_out, float* __restrict__ tok_out,
                        unsigned short* __restrict__ xln_out,
                        const float4* __restrict__ csrc, float4* __restrict__ cdst, long cn4) {
  __shared__ unsigned short T[64 * 72];
  __shared__ int s_idx;
  __shared__ float sbuf[10];
  const int z = blockIdx.z;
  const int t = threadIdx.x;

  if (z == 5) {
    // ---------------- bulk copy: inputs_embeds -> d_out (646 MB traffic) ----------------
    const long tcount = (long)2048 * 256;  // 2048 copy blocks
    long i = ((long)blockIdx.y * gridDim.x + blockIdx.x) * 256 + t;
    for (; i + 3 * tcount < cn4; i += 4 * tcount) {
      float4 v0 = csrc[i];
      float4 v1 = csrc[i + tcount];
      float4 v2 = csrc[i + 2 * tcount];
      float4 v3 = csrc[i + 3 * tcount];
      cdst[i] = v0;
      cdst[i + tcount] = v1;
      cdst[i + 2 * tcount] = v2;
      cdst[i + 3 * tcount] = v3;
    }
    for (; i < cn4; i += tcount) cdst[i] = csrc[i];
    return;
  }

  if (z == 4) {
    // ---------------- prep path ----------------
    const int b = blockIdx.y * gridDim.x + blockIdx.x;
    if (b >= B_) return;
    if (t == 0) s_idx = 0;
    __syncthreads();
    for (int j = t; j < S_; j += 256)
      if (mask[b * S_ + j] != 0) atomicMax(&s_idx, j);
    __syncthreads();
    const int idx = s_idx;
    if (t == 0) idx_out[b] = idx;

    const float4* tokrow = (const float4*)(x_embed + ((long)b * S_ + idx) * D_);
    float4 t0 = tokrow[t * 2];
    float4 t1 = tokrow[t * 2 + 1];
    ((float4*)(tok_out + (long)b * D_))[t * 2] = t0;
    ((float4*)(tok_out + (long)b * D_))[t * 2 + 1] = t1;

    const int n = nobj[b];
    const float inv_n = 1.0f / (float)n;
    float4 s0 = make_float4(0.f, 0.f, 0.f, 0.f), s1 = s0;
    for (int o = 0; o < n; o++) {
      const float4* orow = (const float4*)(obj + ((long)b * 4 + o) * D_);
      float4 q0 = orow[t * 2], q1 = orow[t * 2 + 1];
      s0.x += q0.x; s0.y += q0.y; s0.z += q0.z; s0.w += q0.w;
      s1.x += q1.x; s1.y += q1.y; s1.z += q1.z; s1.w += q1.w;
    }
    float vals[16] = { t0.x, t0.y, t0.z, t0.w, t1.x, t1.y, t1.z, t1.w,
                       s0.x * inv_n, s0.y * inv_n, s0.z * inv_n, s0.w * inv_n,
                       s1.x * inv_n, s1.y * inv_n, s1.z * inv_n, s1.w * inv_n };
    float sum = 0.f, sq = 0.f;
    #pragma unroll
    for (int i = 0; i < 16; i++) { sum += vals[i]; sq += vals[i] * vals[i]; }
    blockReduce2(sum, sq, sbuf);
    const float mu = sum * (1.f / 4096.f);
    const float rstd = rsqrtf(sq * (1.f / 4096.f) - mu * mu + EPS_);
    #pragma unroll
    for (int i = 0; i < 16; i++) {
      int d = (i < 8) ? (t * 8 + i) : (D_ + t * 8 + (i - 8));
      float v = (vals[i] - mu) * rstd * g[d] + bb[d];
      xln_out[(long)b * (2 * D_) + d] = f2bf(v);
    }
    return;
  }

  // ---------------- wcvt path: W[K][2048] f32 -> Wt[2048][K] bf16 ----------------
  const int K = (z == 0) ? 4096 : 2048;
  if ((int)blockIdx.y * 64 >= K) return;
  const float* W = (z == 0) ? w1 : (z == 1) ? w2 : (z == 2) ? w3 : w4;
  unsigned short* O = (z == 0) ? o1 : (z == 1) ? o2 : (z == 2) ? o3 : o4;
  const int k0 = blockIdx.y * 64, n0 = blockIdx.x * 64;
  const int r = t >> 4, c4 = (t & 15) * 4;
  #pragma unroll
  for (int rr = 0; rr < 4; rr++) {
    const int k = rr * 16 + r;
    float4 v = *(const float4*)&W[(long)(k0 + k) * 2048 + n0 + c4];
    T[(c4 + 0) * 72 + k] = f2bf(v.x);
    T[(c4 + 1) * 72 + k] = f2bf(v.y);
    T[(c4 + 2) * 72 + k] = f2bf(v.z);
    T[(c4 + 3) * 72 + k] = f2bf(v.w);
  }
  __syncthreads();
  const int n = t >> 3, k8 = (t & 7) * 8;
  *(uint4*)&O[(long)(n0 + n) * K + k0 + k8]      = *(const uint4*)&T[n * 72 + k8];
  *(uint4*)&O[(long)(n0 + n + 32) * K + k0 + k8] = *(const uint4*)&T[(n + 32) * 72 + k8];
}

// ---------------- deep-pipelined bf16 MFMA GEMM ----------------
// out = epi(A[MxK](bf16) @ Wt[NxK](bf16)^T + bias)
// 4 register stages (load->use distance = 3.5 tiles) + double-buffered LDS,
// ONE barrier per K-tile. Hides ~1500+ cycles of global latency at 1 wave/SIMD.
// Requires ntile (= K/64) to be a multiple of 4 and >= 8 (K = 2048 or 4096 here).

#define DECL_STAGE(s) uint4 sa0_##s, sa1_##s, sb0_##s, sb1_##s;
#define LOAD_STAGE(s, tt) { const long off_ = (long)(tt) << 6; \
  sa0_##s = *(const uint4*)(Ar0 + off_); sa1_##s = *(const uint4*)(Ar1 + off_); \
  sb0_##s = *(const uint4*)(Br0 + off_); sb1_##s = *(const uint4*)(Br1 + off_); }
#define WRITE_STAGE(s, buf) { \
  *(uint4*)&As[buf][srow * LDA + scol]        = sa0_##s; \
  *(uint4*)&As[buf][(srow + 32) * LDA + scol] = sa1_##s; \
  *(uint4*)&Bs[buf][srow * LDA + scol]        = sb0_##s; \
  *(uint4*)&Bs[buf][(srow + 32) * LDA + scol] = sb1_##s; }

// step c: tile t_ = tb+c. Issue loads for t_+4 into stage c (freed last step),
// ds_read frags from buf (c&1), MFMA, write stage (c+1) [tile t_+1] to buf ((c+1)&1), barrier.
#define GEMM_STEP(c, snext, curbuf, nextbuf) { \
  const int t_ = tb + (c); \
  if (t_ + 4 < ntile) LOAD_STAGE(c, t_ + 4) \
  const unsigned short* as_ = As[curbuf]; \
  const unsigned short* bs_ = Bs[curbuf]; \
  bf16x8 af[2][2], bg[2][2]; \
  _Pragma("unroll") \
  for (int kk = 0; kk < 2; kk++) { \
    af[kk][0] = *(const bf16x8*)&as_[(wm + l16) * LDA + kk * 32 + quad * 8]; \
    af[kk][1] = *(const bf16x8*)&as_[(wm + 16 + l16) * LDA + kk * 32 + quad * 8]; \
    bg[kk][0] = *(const bf16x8*)&bs_[(wn + l16) * LDA + kk * 32 + quad * 8]; \
    bg[kk][1] = *(const bf16x8*)&bs_[(wn + 16 + l16) * LDA + kk * 32 + quad * 8]; \
  } \
  _Pragma("unroll") \
  for (int kk = 0; kk < 2; kk++) \
    _Pragma("unroll") \
    for (int mt = 0; mt < 2; mt++) \
      _Pragma("unroll") \
      for (int nt2 = 0; nt2 < 2; nt2++) \
        acc[mt][nt2] = __builtin_amdgcn_mfma_f32_16x16x32_bf16(af[kk][mt], bg[kk][nt2], acc[mt][nt2], 0, 0, 0); \
  if (t_ + 1 < ntile) WRITE_STAGE(snext, nextbuf) \
  __syncthreads(); \
}

template<int GELU, int HAS_RES, int OUT_BF16>
__global__ __launch_bounds__(256)
void gemm_kernel(const unsigned short* __restrict__ A, const unsigned short* __restrict__ Wt,
                 const float* __restrict__ bias, const float* __restrict__ res,
                 void* __restrict__ outp, int M, int N, int K) {
  constexpr int LDA = 72;  // 144 B rows: 16B-aligned, rotates banks by 1 slot/row
  __shared__ __align__(16) unsigned short As[2][64 * LDA];
  __shared__ __align__(16) unsigned short Bs[2][64 * LDA];
  const int tid = threadIdx.x;
  const int m0 = blockIdx.y * 64;
  const int n0 = blockIdx.x * 64;
  const int lane = tid & 63;
  const int wave = tid >> 6;
  const int l16 = lane & 15;
  const int quad = lane >> 4;
  const int wm = (wave & 1) * 32;
  const int wn = (wave >> 1) * 32;
  const int srow = tid >> 3;        // 0..31
  const int scol = (tid & 7) * 8;   // 0..56 (bf16 elems)

  const unsigned short* Ar0 = A  + (long)(m0 + srow) * K + scol;
  const unsigned short* Ar1 = A  + (long)(m0 + srow + 32) * K + scol;
  const unsigned short* Br0 = Wt + (long)(n0 + srow) * K + scol;
  const unsigned short* Br1 = Wt + (long)(n0 + srow + 32) * K + scol;

  f32x4 acc[2][2];
  #pragma unroll
  for (int i = 0; i < 2; i++)
    #pragma unroll
    for (int j = 0; j < 2; j++) acc[i][j] = (f32x4){0.f, 0.f, 0.f, 0.f};

  const int ntile = K >> 6;  // 64 or 32 (multiple of 4)

  DECL_STAGE(0) DECL_STAGE(1) DECL_STAGE(2) DECL_STAGE(3)
  // prologue: 16 loads in flight (tiles 0..3), tile0 -> LDS buf0
  LOAD_STAGE(0, 0) LOAD_STAGE(1, 1) LOAD_STAGE(2, 2) LOAD_STAGE(3, 3)
  WRITE_STAGE(0, 0)
  __syncthreads();

  for (int tb = 0; tb < ntile; tb += 4) {
    GEMM_STEP(0, 1, 0, 1)
    GEMM_STEP(1, 2, 1, 0)
    GEMM_STEP(2, 3, 0, 1)
    GEMM_STEP(3, 0, 1, 0)
  }

  // epilogue: C/D layout col=lane&15, row=quad*4+r
  #pragma unroll
  for (int mt = 0; mt < 2; mt++) {
    #pragma unroll
    for (int nt2 = 0; nt2 < 2; nt2++) {
      const int col = n0 + wn + nt2 * 16 + l16;
      const float bc = bias[col];
      #pragma unroll
      for (int r = 0; r < 4; r++) {
        const int row = m0 + wm + mt * 16 + quad * 4 + r;
        float v = acc[mt][nt2][r] + bc;
        if constexpr (HAS_RES) v += res[(long)row * N + col];
        if constexpr (GELU) v = 0.5f * v * (1.f + erff(v * 0.70710678118654752f));
        if constexpr (OUT_BF16)
          ((unsigned short*)outp)[(long)row * N + col] = f2bf(v);
        else
          ((float*)outp)[(long)row * N + col] = v;
      }
    }
  }
}

// ---------------- LN over 2048, bf16 out (mlp2 input) ----------------
__global__ __launch_bounds__(256)
void ln_bf16_kernel(const float* __restrict__ in, const float* __restrict__ g,
                    const float* __restrict__ bb, unsigned short* __restrict__ out) {
  __shared__ float sbuf[10];
  const int b = blockIdx.x, t = threadIdx.x;
  const float4* row = (const float4*)(in + (long)b * D_);
  float4 v0 = row[t * 2], v1 = row[t * 2 + 1];
  float o[8] = { v0.x, v0.y, v0.z, v0.w, v1.x, v1.y, v1.z, v1.w };
  float sum = 0.f, sq = 0.f;
  #pragma unroll
  for (int i = 0; i < 8; i++) { sum += o[i]; sq += o[i] * o[i]; }
  blockReduce2(sum, sq, sbuf);
  const float mu = sum * (1.f / 2048.f);
  const float rstd = rsqrtf(sq * (1.f / 2048.f) - mu * mu + EPS_);
  const int d0 = t * 8;
  #pragma unroll
  for (int i = 0; i < 8; i++)
    out[(long)b * D_ + d0 + i] = f2bf((o[i] - mu) * rstd * g[d0 + i] + bb[d0 + i]);
}

// ---------------- final LN + scatter into out[b, idx[b], :] ----------------
__global__ __launch_bounds__(256)
void final_kernel(const float* __restrict__ in, const float* __restrict__ g,
                  const float* __restrict__ bb, const int* __restrict__ idxbuf,
                  float* __restrict__ out) {
  __shared__ float sbuf[10];
  const int b = blockIdx.x, t = threadIdx.x;
  const float4* row = (const float4*)(in + (long)b * D_);
  float4 v0 = row[t * 2], v1 = row[t * 2 + 1];
  float o[8] = { v0.x, v0.y, v0.z, v0.w, v1.x, v1.y, v1.z, v1.w };
  float sum = 0.f, sq = 0.f;
  #pragma unroll
  for (int i = 0; i < 8; i++) { sum += o[i]; sq += o[i] * o[i]; }
  blockReduce2(sum, sq, sbuf);
  const float mu = sum * (1.f / 2048.f);
  const float rstd = rsqrtf(sq * (1.f / 2048.f) - mu * mu + EPS_);
  float* orow = out + ((long)b * S_ + idxbuf[b]) * D_;
  const int d0 = t * 8;
  #pragma unroll
  for (int i = 0; i < 8; i++) o[i] = (o[i] - mu) * rstd * g[d0 + i] + bb[d0 + i];
  ((float4*)orow)[t * 2]     = make_float4(o[0], o[1], o[2], o[3]);
  ((float4*)orow)[t * 2 + 1] = make_float4(o[4], o[5], o[6], o[7]);
}

extern "C" void kernel_launch(void* const* d_in, const int* in_sizes, int n_in,
                              void* d_out, int out_size, void* d_ws, size_t ws_size,
                              hipStream_t stream) {
  const float* inputs_embeds = (const float*)d_in[0];
  const float* object_embeds = (const float*)d_in[1];
  const float* mlp1_ln_g = (const float*)d_in[2];
  const float* mlp1_ln_b = (const float*)d_in[3];
  const float* mlp1_w1   = (const float*)d_in[4];
  const float* mlp1_b1   = (const float*)d_in[5];
  const float* mlp1_w2   = (const float*)d_in[6];
  const float* mlp1_b2   = (const float*)d_in[7];
  const float* mlp2_ln_g = (const float*)d_in[8];
  const float* mlp2_ln_b = (const float*)d_in[9];
  const float* mlp2_w1   = (const float*)d_in[10];
  const float* mlp2_b1   = (const float*)d_in[11];
  const float* mlp2_w2   = (const float*)d_in[12];
  const float* mlp2_b2   = (const float*)d_in[13];
  const float* ln_g      = (const float*)d_in[14];
  const float* ln_b      = (const float*)d_in[15];
  const int* mask        = (const int*)d_in[16];
  const int* nobj        = (const int*)d_in[17];

  char* ws = (char*)d_ws;
  int*            idxbuf = (int*)ws;                                   // 512 ints
  float*          tok    = (float*)(ws + 4096);                        // 512x2048 f32
  unsigned short* xln    = (unsigned short*)(ws + 4096 + 4194304);     // 512x4096 bf16
  unsigned short* h1     = (unsigned short*)(ws + 4096 + 8388608);     // 512x2048 bf16
  float*          h2     = (float*)(ws + 4096 + 10485760);             // 512x2048 f32
  unsigned short* x2ln   = (unsigned short*)(ws + 4096 + 14680064);    // 512x2048 bf16
  unsigned short* h3     = (unsigned short*)(ws + 4096 + 16777216);    // 512x2048 bf16
  float*          h4     = (float*)(ws + 4096 + 18874368);             // 512x2048 f32
  char*           wbase  = ws + 4096 + 18874368 + 4194304;             // bf16 Wt buffers
  unsigned short* w1t    = (unsigned short*)(wbase);                   // 2048x4096 bf16 (16 MB)
  unsigned short* w2t    = (unsigned short*)(wbase + 16777216);        // 2048x2048 bf16 (8 MB)
  unsigned short* w3t    = (unsigned short*)(wbase + 25165824);        // 2048x2048 bf16 (8 MB)
  unsigned short* w4t    = (unsigned short*)(wbase + 33554432);        // 2048x2048 bf16 (8 MB)

  const long n4 = (long)B_ * S_ * D_ / 4;  // 20,185,088 float4 (323 MB)

  // one streaming launch: weight cvt (z=0..3) + prep (z=4) + full bulk copy (z=5)
  mega_stream_kernel<<<dim3(32, 64, 6), 256, 0, stream>>>(
      mlp1_w1, mlp1_w2, mlp2_w1, mlp2_w2, w1t, w2t, w3t, w4t,
      inputs_embeds, object_embeds, mask, nobj, mlp1_ln_g, mlp1_ln_b,
      idxbuf, tok, xln,
      (const float4*)inputs_embeds, (float4*)d_out, n4);

  dim3 gg(2048 / 64, B_ / 64);  // (N/64, M/64) = (32, 8) -> 256 blocks
  gemm_kernel<1, 0, 1><<<gg, 256, 0, stream>>>(xln,  w1t, mlp1_b1, nullptr, h1, B_, D_, 2 * D_);
  gemm_kernel<0, 1, 0><<<gg, 256, 0, stream>>>(h1,   w2t, mlp1_b2, tok,     h2, B_, D_, D_);
  ln_bf16_kernel<<<B_, 256, 0, stream>>>(h2, mlp2_ln_g, mlp2_ln_b, x2ln);
  gemm_kernel<1, 0, 1><<<gg, 256, 0, stream>>>(x2ln, w3t, mlp2_b1, nullptr, h3, B_, D_, D_);
  gemm_kernel<0, 1, 0><<<gg, 256, 0, stream>>>(h3,   w4t, mlp2_b2, h2,      h4, B_, D_, D_);
  final_kernel<<<B_, 256, 0, stream>>>(h4, ln_g, ln_b, idxbuf, (float*)d_out);
}